// Round 8
// baseline (178.768 us; speedup 1.0000x reference)
//
#include <hip/hip_runtime.h>

// Focal loss: out[0]=loss_pos, out[1]=loss_neg, out[2]=count_pos, out[3]=count_neg
// ALPHA=2, FPN_POS_FACTOR=(2,1), FPN_NEG_FACTOR=(2,1), ANCHOR_POS_FACTOR={1,1}
// logit0: [8,2,64,128,128] f32 (16,777,216), logit1: [8,2,32,64,64] f32 (2,097,152)
//
// R7 post-mortem: prefetch/VGPR is not the lever (R6 28-VGPR serial beat R7
// 48-VGPR prefetch). Neg kernel is BW-capped (~2.7 TB/s HBM + L3 overlap);
// the addressable cost is the serial finalize kernel (~5-8us launch+latency).
// R8: single fused kernel, last-block-done reduction; pos-gather in block 0
// runs concurrently with neg blocks. Only extra launch: 4-byte counter memset.

#define LOG2E 1.44269504088896340736f
#define LN2   0.69314718055994530942f
#define NEG_BLOCKS 4608   // 4096 L0 + 512 L1, 1024 quads (4096 floats) each

__device__ __forceinline__ float exp2_hw(float x) { return __builtin_amdgcn_exp2f(x); }
__device__ __forceinline__ float log2_hw(float x) { return __builtin_amdgcn_logf(x); }  // v_log_f32 = log2
__device__ __forceinline__ float rcp_hw(float x)  { return __builtin_amdgcn_rcpf(x); }

// w = sigmoid(x)^2*[g==-1]; loss += softplus(x)*w; count += w
__device__ __forceinline__ void neg_elem(float x, float g, float& lsum, float& csum) {
    float z  = fmaxf(x * LOG2E, -43.0f);    // clamp: below this weight < 1e-26
    float t  = exp2_hw(-z);                 // e^{-x}
    float u  = 1.0f + t;
    float r  = rcp_hw(u);                   // sigmoid(x)
    float w  = (g == -1.0f) ? r * r : 0.0f; // prob^2 * negmask
    float sp = LN2 * (z + log2_hw(u));      // softplus(x)
    csum += w;
    lsum += sp * w;
}

__device__ __forceinline__ void neg_quad(float4 x4, float4 g4, float& lsum, float& csum) {
    neg_elem(x4.x, g4.x, lsum, csum);
    neg_elem(x4.y, g4.y, lsum, csum);
    neg_elem(x4.z, g4.z, lsum, csum);
    neg_elem(x4.w, g4.w, lsum, csum);
}

__global__ void __launch_bounds__(256) fused_kernel(
        const float4* __restrict__ x0, const float4* __restrict__ g0,
        const float4* __restrict__ x1, const float4* __restrict__ g1,
        int nblk0,                                  // 4096
        const float* __restrict__ logit0, const int* __restrict__ coord0,
        const float* __restrict__ logit1, const int* __restrict__ coord1,
        float* __restrict__ ws,                     // [NEG_BLOCKS*2] partials
        unsigned* __restrict__ counter,             // zeroed before launch
        float* __restrict__ out) {
    const int tid  = threadIdx.x;
    const int lane = tid & 63;
    const int wav  = tid >> 6;
    __shared__ float sa[4], sb[4];

    if (blockIdx.x == 0) {
        // ---- positive (gathered) term: 1024 items, 4 per thread ----
        float lp = 0.0f, cp = 0.0f;
        #pragma unroll
        for (int k = 0; k < 4; ++k) {
            const int item  = tid + k * 256;
            const int level = (item >= 512);
            const int jj    = level ? (item - 512) : item;
            const int b     = jj >> 6;  // P = 64
            const int* cptr = (level ? coord1 : coord0) + jj * 4;
            int c0 = cptr[0], c1 = cptr[1], c2 = cptr[2], c3 = cptr[3];
            const bool v = (c0 > -1);
            const float valid = v ? 1.0f : 0.0f;
            if (!v) { c0 = 0; c1 = 0; c2 = 0; c3 = 0; }
            long off; const float* lg; float posf;
            if (!level) {
                off = ((((long)b * 2 + c0) * 64 + c1) * 128 + c2) * 128 + c3;  // [8][2][64][128][128]
                lg = logit0; posf = 2.0f;
            } else {
                off = ((((long)b * 2 + c0) * 32 + c1) * 64 + c2) * 64 + c3;    // [8][2][32][64][64]
                lg = logit1; posf = 1.0f;
            }
            const float x = lg[off];
            // w = (1-sigmoid(x))^2 * valid;  -log_sigmoid(x) = softplus(-x)
            float z  = fmaxf(-x * LOG2E, -43.0f);
            float t  = exp2_hw(-z);
            float u  = 1.0f + t;
            float r  = rcp_hw(u);               // 1 - sigmoid(x)
            float w  = r * r * valid;
            float sp = LN2 * (z + log2_hw(u));  // softplus(-x)
            lp += sp * w * posf;                // ANCHOR_POS_FACTOR = 1
            cp += w;
        }
        #pragma unroll
        for (int off = 32; off > 0; off >>= 1) {
            lp += __shfl_down(lp, off);
            cp += __shfl_down(cp, off);
        }
        if (lane == 0) { sa[wav] = lp; sb[wav] = cp; }
        __syncthreads();
        if (tid == 0) {
            out[0] = sa[0] + sa[1] + sa[2] + sa[3];
            out[2] = sb[0] + sb[1] + sb[2] + sb[3];
        }
        return;
    }

    // ---- negative term: blocks 1..NEG_BLOCKS ----
    const int bid = blockIdx.x - 1;
    const float4* __restrict__ xp;
    const float4* __restrict__ gp;
    float f;
    int idx;
    if (bid < nblk0) {
        xp = x0; gp = g0; f = 2.0f;
        idx = bid * 1024 + wav * 256 + lane;
    } else {
        xp = x1; gp = g1; f = 1.0f;
        idx = (bid - nblk0) * 1024 + wav * 256 + lane;
    }
    float4 xa = xp[idx      ];
    float4 ga = gp[idx      ];
    float4 xb = xp[idx +  64];
    float4 gb = gp[idx +  64];
    float4 xc = xp[idx + 128];
    float4 gc = gp[idx + 128];
    float4 xd = xp[idx + 192];
    float4 gd = gp[idx + 192];

    float lsum = 0.0f, csum = 0.0f;
    neg_quad(xa, ga, lsum, csum);
    neg_quad(xb, gb, lsum, csum);
    neg_quad(xc, gc, lsum, csum);
    neg_quad(xd, gd, lsum, csum);
    lsum *= f;  // FPN_NEG_FACTOR baked per block

    #pragma unroll
    for (int off = 32; off > 0; off >>= 1) {
        lsum += __shfl_down(lsum, off);
        csum += __shfl_down(csum, off);
    }
    if (lane == 0) { sa[wav] = lsum; sb[wav] = csum; }
    __syncthreads();

    __shared__ int slast;
    if (tid == 0) {
        // agent-scope stores so the (possibly other-XCD) reducer sees them
        __hip_atomic_store(&ws[bid * 2],     sa[0] + sa[1] + sa[2] + sa[3],
                           __ATOMIC_RELAXED, __HIP_MEMORY_SCOPE_AGENT);
        __hip_atomic_store(&ws[bid * 2 + 1], sb[0] + sb[1] + sb[2] + sb[3],
                           __ATOMIC_RELAXED, __HIP_MEMORY_SCOPE_AGENT);
        __threadfence();  // release partials before the counter bump
        unsigned prev = atomicAdd(counter, 1u);  // device-scope by default
        slast = (prev == (unsigned)(NEG_BLOCKS - 1));
    }
    __syncthreads();

    if (slast) {
        __threadfence();  // acquire
        float ln = 0.0f, cn = 0.0f;
        for (int i = tid; i < NEG_BLOCKS; i += 256) {   // fixed order -> deterministic
            ln += __hip_atomic_load(&ws[i * 2],     __ATOMIC_RELAXED, __HIP_MEMORY_SCOPE_AGENT);
            cn += __hip_atomic_load(&ws[i * 2 + 1], __ATOMIC_RELAXED, __HIP_MEMORY_SCOPE_AGENT);
        }
        #pragma unroll
        for (int off = 32; off > 0; off >>= 1) {
            ln += __shfl_down(ln, off);
            cn += __shfl_down(cn, off);
        }
        __syncthreads();  // sa/sb reuse
        if (lane == 0) { sa[wav] = ln; sb[wav] = cn; }
        __syncthreads();
        if (tid == 0) {
            out[1] = sa[0] + sa[1] + sa[2] + sa[3];
            out[3] = sb[0] + sb[1] + sb[2] + sb[3];
        }
    }
}

extern "C" void kernel_launch(void* const* d_in, const int* in_sizes, int n_in,
                              void* d_out, int out_size, void* d_ws, size_t ws_size,
                              hipStream_t stream) {
    const float* logit0 = (const float*)d_in[0];
    const float* logit1 = (const float*)d_in[1];
    const float* gt0    = (const float*)d_in[2];
    const float* gt1    = (const float*)d_in[3];
    const int*   coord0 = (const int*)d_in[4];
    const int*   coord1 = (const int*)d_in[5];
    float* out = (float*)d_out;

    float* ws = (float*)d_ws;                                // NEG_BLOCKS float2 partials
    unsigned* counter = (unsigned*)((char*)d_ws + NEG_BLOCKS * 2 * sizeof(float));

    const int n0 = in_sizes[0];   // 16,777,216 floats -> 4096 neg blocks
    const int nblk0 = n0 >> 12;   // 4096 floats per block

    (void)hipMemsetAsync(counter, 0, sizeof(unsigned), stream);

    fused_kernel<<<NEG_BLOCKS + 1, 256, 0, stream>>>(
        (const float4*)logit0, (const float4*)gt0,
        (const float4*)logit1, (const float4*)gt1, nblk0,
        logit0, coord0, logit1, coord1,
        ws, counter, out);
}

// Round 9
// 32.955 us; speedup vs baseline: 5.4246x; 5.4246x over previous
//
#include <hip/hip_runtime.h>

// Focal loss: out[0]=loss_pos, out[1]=loss_neg, out[2]=count_pos, out[3]=count_neg
// ALPHA=2, FPN_POS_FACTOR=(2,1), FPN_NEG_FACTOR=(2,1), ANCHOR_POS_FACTOR={1,1}
// logit0: [8,2,64,128,128] f32 (16,777,216), logit1: [8,2,32,64,64] f32 (2,097,152)
//
// R8 post-mortem: last-block-done fusion = 178us (cross-XCD fence+atomic per
// block serializes ~60ns each x4608). Revert to R6 two-kernel structure.
// R9 change: VGPR=28 showed the 8 staged loads were sunk into load->use
// pairs (~2-3KB/wave in flight; Little's law needs ~22KB/CU for 6.3TB/s).
// sched_barrier(0) after the load cluster pins all 8 loads before compute.

#define LOG2E 1.44269504088896340736f
#define LN2   0.69314718055994530942f

__device__ __forceinline__ float exp2_hw(float x) { return __builtin_amdgcn_exp2f(x); }
__device__ __forceinline__ float log2_hw(float x) { return __builtin_amdgcn_logf(x); }  // v_log_f32 = log2
__device__ __forceinline__ float rcp_hw(float x)  { return __builtin_amdgcn_rcpf(x); }

// w = sigmoid(x)^2*[g==-1]; loss += softplus(x)*w; count += w
__device__ __forceinline__ void neg_elem(float x, float g, float& lsum, float& csum) {
    float z  = fmaxf(x * LOG2E, -43.0f);    // clamp: below this weight < 1e-26
    float t  = exp2_hw(-z);                 // e^{-x}
    float u  = 1.0f + t;
    float r  = rcp_hw(u);                   // sigmoid(x)
    float w  = (g == -1.0f) ? r * r : 0.0f; // prob^2 * negmask
    float sp = LN2 * (z + log2_hw(u));      // softplus(x)
    csum += w;
    lsum += sp * w;
}

__device__ __forceinline__ void neg_quad(float4 x4, float4 g4, float& lsum, float& csum) {
    neg_elem(x4.x, g4.x, lsum, csum);
    neg_elem(x4.y, g4.y, lsum, csum);
    neg_elem(x4.z, g4.z, lsum, csum);
    neg_elem(x4.w, g4.w, lsum, csum);
}

// Each 256-thread block covers 1024 float4-quads (4096 floats) of one level.
// Blocks [0,nblk0) -> L0, rest -> L1. Partials to ws[blk] (no atomics).
__global__ void __launch_bounds__(256, 4) neg_loss_kernel(
        const float4* __restrict__ x0, const float4* __restrict__ g0,
        const float4* __restrict__ x1, const float4* __restrict__ g1,
        int nblk0, float2* __restrict__ ws) {
    const int lane = threadIdx.x & 63;
    const int wav  = threadIdx.x >> 6;
    const float4* __restrict__ xp;
    const float4* __restrict__ gp;
    float f;
    int idx;
    if ((int)blockIdx.x < nblk0) {
        xp = x0; gp = g0; f = 2.0f;
        idx = blockIdx.x * 1024 + wav * 256 + lane;
    } else {
        xp = x1; gp = g1; f = 1.0f;
        idx = (blockIdx.x - nblk0) * 1024 + wav * 256 + lane;
    }
    // 8 independent 16B loads; sched_barrier(0) forbids the scheduler from
    // sinking any of them below the compute -> all 8 in flight (8KB/wave).
    float4 xa = xp[idx      ];
    float4 xb = xp[idx +  64];
    float4 xc = xp[idx + 128];
    float4 xd = xp[idx + 192];
    float4 ga = gp[idx      ];
    float4 gb = gp[idx +  64];
    float4 gc = gp[idx + 128];
    float4 gd = gp[idx + 192];
    __builtin_amdgcn_sched_barrier(0);

    float lsum = 0.0f, csum = 0.0f;
    neg_quad(xa, ga, lsum, csum);
    neg_quad(xb, gb, lsum, csum);
    neg_quad(xc, gc, lsum, csum);
    neg_quad(xd, gd, lsum, csum);
    lsum *= f;  // FPN_NEG_FACTOR baked per block

    #pragma unroll
    for (int off = 32; off > 0; off >>= 1) {
        lsum += __shfl_down(lsum, off);
        csum += __shfl_down(csum, off);
    }
    __shared__ float sl[4], sc[4];
    if (lane == 0) { sl[wav] = lsum; sc[wav] = csum; }
    __syncthreads();
    if (threadIdx.x == 0) {
        ws[blockIdx.x] = make_float2(sl[0] + sl[1] + sl[2] + sl[3],
                                     sc[0] + sc[1] + sc[2] + sc[3]);
    }
}

// One block, 1024 threads: positive (gathered) term + reduce ws partials.
__global__ void __launch_bounds__(1024) finalize_kernel(
        const float* __restrict__ logit0, const int* __restrict__ coord0,
        const float* __restrict__ logit1, const int* __restrict__ coord1,
        const float2* __restrict__ ws, int nblk,
        float* __restrict__ out) {
    const int j = threadIdx.x;
    float lp = 0.0f, cp = 0.0f;
    {
        const int level = (j >= 512);
        const int jj = level ? (j - 512) : j;
        const int b = jj >> 6;  // P = 64
        const int* cptr = (level ? coord1 : coord0) + jj * 4;
        int c0 = cptr[0], c1 = cptr[1], c2 = cptr[2], c3 = cptr[3];
        const bool v = (c0 > -1);
        const float valid = v ? 1.0f : 0.0f;
        if (!v) { c0 = 0; c1 = 0; c2 = 0; c3 = 0; }
        long off;
        const float* lg;
        float posf;
        if (!level) {
            off = ((((long)b * 2 + c0) * 64 + c1) * 128 + c2) * 128 + c3;  // [8][2][64][128][128]
            lg = logit0; posf = 2.0f;
        } else {
            off = ((((long)b * 2 + c0) * 32 + c1) * 64 + c2) * 64 + c3;   // [8][2][32][64][64]
            lg = logit1; posf = 1.0f;
        }
        const float x = lg[off];
        // w = (1-sigmoid(x))^2 * valid;  -log_sigmoid(x) = softplus(-x)
        float z  = fmaxf(-x * LOG2E, -43.0f);
        float t  = exp2_hw(-z);                 // e^{x}
        float u  = 1.0f + t;
        float r  = rcp_hw(u);                   // 1 - sigmoid(x)
        float w  = r * r * valid;
        float sp = LN2 * (z + log2_hw(u));      // softplus(-x)
        lp = sp * w * posf;                     // w2 = ANCHOR_POS_FACTOR = 1
        cp = w;
    }
    float ln = 0.0f, cn = 0.0f;
    for (int i = j; i < nblk; i += 1024) {
        float2 p = ws[i];
        ln += p.x;
        cn += p.y;
    }
    #pragma unroll
    for (int off = 32; off > 0; off >>= 1) {
        lp += __shfl_down(lp, off);
        cp += __shfl_down(cp, off);
        ln += __shfl_down(ln, off);
        cn += __shfl_down(cn, off);
    }
    __shared__ float sl[16], sc[16], sln[16], scn[16];
    int wav = threadIdx.x >> 6, lane = threadIdx.x & 63;
    if (lane == 0) { sl[wav] = lp; sc[wav] = cp; sln[wav] = ln; scn[wav] = cn; }
    __syncthreads();
    if (threadIdx.x == 0) {
        float tl = 0.0f, tc = 0.0f, tln = 0.0f, tcn = 0.0f;
        #pragma unroll
        for (int i = 0; i < 16; ++i) { tl += sl[i]; tc += sc[i]; tln += sln[i]; tcn += scn[i]; }
        out[0] = tl;
        out[1] = tln;
        out[2] = tc;
        out[3] = tcn;
    }
}

extern "C" void kernel_launch(void* const* d_in, const int* in_sizes, int n_in,
                              void* d_out, int out_size, void* d_ws, size_t ws_size,
                              hipStream_t stream) {
    const float* logit0 = (const float*)d_in[0];
    const float* logit1 = (const float*)d_in[1];
    const float* gt0    = (const float*)d_in[2];
    const float* gt1    = (const float*)d_in[3];
    const int*   coord0 = (const int*)d_in[4];
    const int*   coord1 = (const int*)d_in[5];
    float* out = (float*)d_out;
    float2* ws = (float2*)d_ws;

    const int n0 = in_sizes[0];  // 16,777,216 = 4096 blocks * 4096 floats
    const int n1 = in_sizes[1];  //  2,097,152 =  512 blocks * 4096 floats
    const int nblk0 = n0 >> 12;
    const int nblk1 = n1 >> 12;
    const int nblk = nblk0 + nblk1;

    neg_loss_kernel<<<nblk, 256, 0, stream>>>(
        (const float4*)logit0, (const float4*)gt0,
        (const float4*)logit1, (const float4*)gt1, nblk0, ws);
    finalize_kernel<<<1, 1024, 0, stream>>>(
        logit0, coord0, logit1, coord1, ws, nblk, out);
}